// Round 1
// 143.996 us; speedup vs baseline: 1.0920x; 1.0920x over previous
//
#include <hip/hip_runtime.h>

// ESN final-state, fused single-kernel version.
//
// |W_res_diag| < 0.95 strictly -> s_t = tanh(u_t + d*s_{t-1}) is a per-unit
// contraction (factor <= 0.95 per step). Starting from s=0 at t = T-128
// gives truncation error <= 0.95^128 ~ 1.4e-3, well below the 2e-2
// threshold (prev version used 256 steps -> absmax 0.0; 128 keeps 14x margin
// and halves both the GEMM and the serial chain).
//
// Fusion rationale (rocprof): the two-kernel version paid a second launch +
// a global g_proj round trip; cross-kernel the L2 is flushed, so scan loads
// came from L3/HBM at ~500-900 cy latency against a 28 cy/step chain.
// Here projections live in LDS (ds_read ~120 cy, fully hidden).
//
// Block = 256 threads, owns 16 reservoir units:
//   phase 1: thread (u = tid&15, ks = tid>>4) computes projections for unit
//            b*16+u, timesteps ks*8..ks*8+7 (1024 FMA/thread). X rows are
//            16-lane broadcast loads (4 cache lines per wave instr, L2/L3
//            resident: 64 blocks x 64 KB tile). W row L1-resident (16 threads
//            share it). Writes to p_lds[128][17] (pad -> conflict-free).
//   phase 2: lanes 0..15 run the 128-step chain:
//            tanh(z) = 1 - 2/(exp2(c*z)+1), c = 2*log2(e); per-step chain is
//            fma -> exp2 -> add -> rcp -> fma, projections pre-scaled by c.

#define K_STEPS 128
#define RES 1024
#define INP 128
#define UPB 16                      // units per block
#define C2LOG2E 2.885390081777927f  // 2*log2(e)

__global__ __launch_bounds__(256) void esn_fused(
    const float* __restrict__ X, const float* __restrict__ W,
    const float* __restrict__ d, float* __restrict__ out,
    int t0, int nsteps) {
  __shared__ float p_lds[K_STEPS][UPB + 1];  // +1 pad: conflict-free scan reads
  const int tid = threadIdx.x;
  const int u = tid & (UPB - 1);
  const int ks = tid >> 4;  // 0..15, 8 timesteps each
  const int unit = blockIdx.x * UPB + u;

  const float dval = d[unit];  // hoisted: ready long before phase 2

  // ---- phase 1: projections ----
  const int kbase = ks * 8;
  if (kbase < nsteps) {
    const float4* __restrict__ Wr = (const float4*)(W + (size_t)unit * INP);
    const float4* __restrict__ Xg =
        (const float4*)(X + (size_t)(t0 + kbase) * INP);
    if (nsteps - kbase >= 8) {
      float acc[8];
#pragma unroll
      for (int t = 0; t < 8; ++t) acc[t] = 0.0f;
#pragma unroll 8
      for (int j = 0; j < INP / 4; ++j) {
        const float4 w = Wr[j];
#pragma unroll
        for (int t = 0; t < 8; ++t) {
          const float4 x = Xg[t * (INP / 4) + j];
          acc[t] += w.x * x.x + w.y * x.y + w.z * x.z + w.w * x.w;
        }
      }
#pragma unroll
      for (int t = 0; t < 8; ++t)
        p_lds[kbase + t][u] = C2LOG2E * acc[t];
    } else {
      // Generic tail (only if T < 128; not hit at T = 200000).
      const int kcnt = nsteps - kbase;
      for (int t = 0; t < kcnt; ++t) {
        float a = 0.0f;
        for (int j = 0; j < INP / 4; ++j) {
          const float4 w = Wr[j];
          const float4 x = Xg[t * (INP / 4) + j];
          a += w.x * x.x + w.y * x.y + w.z * x.z + w.w * x.w;
        }
        p_lds[kbase + t][u] = C2LOG2E * a;
      }
    }
  }
  __syncthreads();

  // ---- phase 2: serial scan, lanes 0..15 of wave 0 ----
  if (tid < UPB) {
    const float dc = C2LOG2E * dval;
    float s = 0.0f;
    if (nsteps == K_STEPS) {
#pragma unroll 16
      for (int k = 0; k < K_STEPS; ++k) {
        const float z = p_lds[k][u] + dc * s;          // v_fma
        const float e = __builtin_amdgcn_exp2f(z);     // v_exp_f32
        const float r = __builtin_amdgcn_rcpf(e + 1.0f);
        s = __builtin_fmaf(-2.0f, r, 1.0f);            // v_fma
      }
    } else {
      for (int k = 0; k < nsteps; ++k) {
        const float z = p_lds[k][u] + dc * s;
        const float e = __builtin_amdgcn_exp2f(z);
        const float r = __builtin_amdgcn_rcpf(e + 1.0f);
        s = __builtin_fmaf(-2.0f, r, 1.0f);
      }
    }
    out[unit] = s;
  }
}

extern "C" void kernel_launch(void* const* d_in, const int* in_sizes, int n_in,
                              void* d_out, int out_size, void* d_ws,
                              size_t ws_size, hipStream_t stream) {
  const float* X = (const float*)d_in[0];       // [T, 128]
  const float* W_in = (const float*)d_in[1];    // [1024, 128]
  const float* W_diag = (const float*)d_in[2];  // [1024]
  float* out = (float*)d_out;                   // [1024]

  const int T = in_sizes[0] / INP;  // 200000
  const int nsteps = (T < K_STEPS) ? T : K_STEPS;
  const int t0 = T - nsteps;

  esn_fused<<<RES / UPB, 256, 0, stream>>>(X, W_in, W_diag, out, t0, nsteps);
}